// Round 2
// baseline (22090.430 us; speedup 1.0000x reference)
//
#include <hip/hip_runtime.h>

#define NDIM 2
#define NCELLS 200
#define BATCH 128
#define NPTS (BATCH * NCELLS)
#define XROW (2 + NCELLS * NDIM + 5) /* 407 */
#define DT_F 0.001f

// LDS float offsets (16B-aligned rows where it matters)
#define OFF_W0 0      /* 32  */
#define OFF_B0 32     /* 16  */
#define OFF_W1 48     /* 512 (rows of 16) */
#define OFF_B1 560    /* 32  */
#define OFF_W2 592    /* 1024 (rows of 32) */
#define OFF_B2 1616   /* 32  */
#define OFF_W3 1648   /* 512 (rows of 32) */
#define OFF_B3 2160   /* 16  */
#define OFF_W4 2176   /* 16  */
#define NW_TOT 2192

__device__ __forceinline__ float softplus_f(float z) {
    float e = __expf(-fabsf(z));
    return fmaxf(z, 0.0f) + __logf(1.0f + e);
}

__device__ __forceinline__ void lds_copy(float* dst, const float* src, int n, int tid) {
    for (int i = tid; i < n; i += 64) dst[i] = src[i];
}

__global__ void __launch_bounds__(64, 1) phinn_kernel(
    const float* __restrict__ w0, const float* __restrict__ b0,
    const float* __restrict__ w1, const float* __restrict__ b1,
    const float* __restrict__ w2, const float* __restrict__ b2,
    const float* __restrict__ w3, const float* __restrict__ b3,
    const float* __restrict__ w4, const float* __restrict__ b4,
    const float* __restrict__ wt, const float* __restrict__ x,
    float* __restrict__ out)
{
    __shared__ float W[NW_TOT];
    const int lt = threadIdx.x;
    lds_copy(W + OFF_W0, w0, 32, lt);
    lds_copy(W + OFF_B0, b0, 16, lt);
    lds_copy(W + OFF_W1, w1, 512, lt);
    lds_copy(W + OFF_B1, b1, 32, lt);
    lds_copy(W + OFF_W2, w2, 1024, lt);
    lds_copy(W + OFF_B2, b2, 32, lt);
    lds_copy(W + OFF_W3, w3, 512, lt);
    lds_copy(W + OFF_B3, b3, 16, lt);
    lds_copy(W + OFF_W4, w4, 16, lt);
    __syncthreads();

    const int tid = blockIdx.x * 64 + lt;
    const int bi = tid / NCELLS;
    const int ci = tid - bi * NCELLS;
    const float* xr = x + bi * XROW;

    float y0 = xr[2 + ci * 2 + 0];
    float y1 = xr[2 + ci * 2 + 1];
    float ts = xr[0];
    const float sp0    = xr[XROW - 5];
    const float sg_lo0 = xr[XROW - 4], sg_lo1 = xr[XROW - 3];
    const float sg_hi0 = xr[XROW - 2], sg_hi1 = xr[XROW - 1];

    const float wt00 = wt[0], wt01 = wt[1], wt10 = wt[2], wt11 = wt[3];
    // both-branch tilt, selected per step
    const float tl0 = sg_lo0 * wt00 + sg_lo1 * wt01;
    const float tl1 = sg_lo0 * wt10 + sg_lo1 * wt11;
    const float th0 = sg_hi0 * wt00 + sg_hi1 * wt01;
    const float th1 = sg_hi0 * wt10 + sg_hi1 * wt11;

    const int nsteps = (int)((x[1] - x[0]) / DT_F + 0.5f);

    #pragma unroll 1
    for (int it = 0; it < nsteps; ++it) {
        const bool lo = ts < sp0;
        const float tilt0 = lo ? tl0 : th0;
        const float tilt1 = lo ? tl1 : th1;

        // ---------- forward ----------
        float a1[16];
        {
            #pragma unroll
            for (int j = 0; j < 16; j += 2) {
                float4 wv = *(const float4*)&W[OFF_W0 + 2 * j];
                float z0 = fmaf(wv.x, y0, fmaf(wv.y, y1, W[OFF_B0 + j]));
                float z1 = fmaf(wv.z, y0, fmaf(wv.w, y1, W[OFF_B0 + j + 1]));
                a1[j] = softplus_f(z0);
                a1[j + 1] = softplus_f(z1);
            }
        }
        float a2[32];
        #pragma unroll
        for (int j = 0; j < 32; ++j) {
            float z = W[OFF_B1 + j];
            #pragma unroll
            for (int k = 0; k < 16; k += 4) {
                float4 wv = *(const float4*)&W[OFF_W1 + 16 * j + k];
                z = fmaf(wv.x, a1[k], z);
                z = fmaf(wv.y, a1[k + 1], z);
                z = fmaf(wv.z, a1[k + 2], z);
                z = fmaf(wv.w, a1[k + 3], z);
            }
            a2[j] = softplus_f(z);
        }
        float a3[32];
        #pragma unroll
        for (int j = 0; j < 32; ++j) {
            float z = W[OFF_B2 + j];
            #pragma unroll
            for (int k = 0; k < 32; k += 4) {
                float4 wv = *(const float4*)&W[OFF_W2 + 32 * j + k];
                z = fmaf(wv.x, a2[k], z);
                z = fmaf(wv.y, a2[k + 1], z);
                z = fmaf(wv.z, a2[k + 2], z);
                z = fmaf(wv.w, a2[k + 3], z);
            }
            a3[j] = softplus_f(z);
        }
        float a4[16];
        #pragma unroll
        for (int j = 0; j < 16; ++j) {
            float z = W[OFF_B3 + j];
            #pragma unroll
            for (int k = 0; k < 32; k += 4) {
                float4 wv = *(const float4*)&W[OFF_W3 + 32 * j + k];
                z = fmaf(wv.x, a3[k], z);
                z = fmaf(wv.y, a3[k + 1], z);
                z = fmaf(wv.z, a3[k + 2], z);
                z = fmaf(wv.w, a3[k + 3], z);
            }
            a4[j] = softplus_f(z);
        }

        // ---------- backward:  sigma(z) = 1 - exp(-softplus(z)) ----------
        float g4[16];
        {
            #pragma unroll
            for (int j = 0; j < 16; j += 4) {
                float4 wv = *(const float4*)&W[OFF_W4 + j];
                g4[j]     = wv.x * (1.0f - __expf(-a4[j]));
                g4[j + 1] = wv.y * (1.0f - __expf(-a4[j + 1]));
                g4[j + 2] = wv.z * (1.0f - __expf(-a4[j + 2]));
                g4[j + 3] = wv.w * (1.0f - __expf(-a4[j + 3]));
            }
        }
        // g3[k] = (sum_j w3[j,k] g4[j]) * sig(a3[k])   — stream rows of w3
        float g3[32];
        #pragma unroll
        for (int k = 0; k < 32; ++k) g3[k] = 0.0f;
        #pragma unroll
        for (int j = 0; j < 16; ++j) {
            const float gj = g4[j];
            #pragma unroll
            for (int k = 0; k < 32; k += 4) {
                float4 wv = *(const float4*)&W[OFF_W3 + 32 * j + k];
                g3[k]     = fmaf(wv.x, gj, g3[k]);
                g3[k + 1] = fmaf(wv.y, gj, g3[k + 1]);
                g3[k + 2] = fmaf(wv.z, gj, g3[k + 2]);
                g3[k + 3] = fmaf(wv.w, gj, g3[k + 3]);
            }
        }
        #pragma unroll
        for (int k = 0; k < 32; ++k) g3[k] *= (1.0f - __expf(-a3[k]));

        float g2[32];
        #pragma unroll
        for (int k = 0; k < 32; ++k) g2[k] = 0.0f;
        #pragma unroll
        for (int j = 0; j < 32; ++j) {
            const float gj = g3[j];
            #pragma unroll
            for (int k = 0; k < 32; k += 4) {
                float4 wv = *(const float4*)&W[OFF_W2 + 32 * j + k];
                g2[k]     = fmaf(wv.x, gj, g2[k]);
                g2[k + 1] = fmaf(wv.y, gj, g2[k + 1]);
                g2[k + 2] = fmaf(wv.z, gj, g2[k + 2]);
                g2[k + 3] = fmaf(wv.w, gj, g2[k + 3]);
            }
        }
        #pragma unroll
        for (int k = 0; k < 32; ++k) g2[k] *= (1.0f - __expf(-a2[k]));

        float g1[16];
        #pragma unroll
        for (int k = 0; k < 16; ++k) g1[k] = 0.0f;
        #pragma unroll
        for (int j = 0; j < 32; ++j) {
            const float gj = g2[j];
            #pragma unroll
            for (int k = 0; k < 16; k += 4) {
                float4 wv = *(const float4*)&W[OFF_W1 + 16 * j + k];
                g1[k]     = fmaf(wv.x, gj, g1[k]);
                g1[k + 1] = fmaf(wv.y, gj, g1[k + 1]);
                g1[k + 2] = fmaf(wv.z, gj, g1[k + 2]);
                g1[k + 3] = fmaf(wv.w, gj, g1[k + 3]);
            }
        }
        float gy0 = 0.0f, gy1 = 0.0f;
        #pragma unroll
        for (int j = 0; j < 16; j += 2) {
            float4 wv = *(const float4*)&W[OFF_W0 + 2 * j];
            const float s0 = g1[j]     * (1.0f - __expf(-a1[j]));
            const float s1 = g1[j + 1] * (1.0f - __expf(-a1[j + 1]));
            gy0 = fmaf(wv.x, s0, gy0);
            gy1 = fmaf(wv.y, s0, gy1);
            gy0 = fmaf(wv.z, s1, gy0);
            gy1 = fmaf(wv.w, s1, gy1);
        }

        y0 = fmaf(-(gy0 + tilt0), DT_F, y0);
        y1 = fmaf(-(gy1 + tilt1), DT_F, y1);
        ts += DT_F;
    }

    out[2 * tid + 0] = y0;
    out[2 * tid + 1] = y1;
}

extern "C" void kernel_launch(void* const* d_in, const int* in_sizes, int n_in,
                              void* d_out, int out_size, void* d_ws, size_t ws_size,
                              hipStream_t stream) {
    (void)in_sizes; (void)n_in; (void)d_ws; (void)ws_size; (void)out_size;
    const float* w0 = (const float*)d_in[0];
    const float* b0 = (const float*)d_in[1];
    const float* w1 = (const float*)d_in[2];
    const float* b1 = (const float*)d_in[3];
    const float* w2 = (const float*)d_in[4];
    const float* b2 = (const float*)d_in[5];
    const float* w3 = (const float*)d_in[6];
    const float* b3 = (const float*)d_in[7];
    const float* w4 = (const float*)d_in[8];
    const float* b4 = (const float*)d_in[9];
    const float* wt = (const float*)d_in[10];
    const float* x  = (const float*)d_in[11];
    float* out = (float*)d_out;

    dim3 grid(NPTS / 64), block(64);
    hipLaunchKernelGGL(phinn_kernel, grid, block, 0, stream,
                       w0, b0, w1, b1, w2, b2, w3, b3, w4, b4, wt, x, out);
}

// Round 3
// 10294.582 us; speedup vs baseline: 2.1458x; 2.1458x over previous
//
#include <hip/hip_runtime.h>

#define NDIM 2
#define NCELLS 200
#define BATCH 128
#define NPTS (BATCH * NCELLS)
#define XROW (2 + NCELLS * NDIM + 5) /* 407 */
#define DT_F 0.001f

// LDS float offsets (16B-aligned rows)
#define OFF_W0 0      /* 32  */
#define OFF_B0 32     /* 16  */
#define OFF_W1 48     /* 512 (rows of 16) */
#define OFF_B1 560    /* 32  */
#define OFF_W2 592    /* 1024 (rows of 32) */
#define OFF_B2 1616   /* 32  */
#define OFF_W3 1648   /* 512 (rows of 32) */
#define OFF_B3 2160   /* 16  */
#define OFF_W4 2176   /* 16  */
#define NW_TOT 2192

__device__ __forceinline__ float softplus_f(float z) {
    float e = __expf(-fabsf(z));
    return fmaxf(z, 0.0f) + __logf(1.0f + e);
}

__device__ __forceinline__ void lds_copy(float* dst, const float* src, int n, int tid) {
    for (int i = tid; i < n; i += 64) dst[i] = src[i];
}

__global__ void __launch_bounds__(64, 1) phinn_kernel(
    const float* __restrict__ w0, const float* __restrict__ b0,
    const float* __restrict__ w1, const float* __restrict__ b1,
    const float* __restrict__ w2, const float* __restrict__ b2,
    const float* __restrict__ w3, const float* __restrict__ b3,
    const float* __restrict__ w4, const float* __restrict__ b4,
    const float* __restrict__ wt, const float* __restrict__ x,
    float* __restrict__ out)
{
    __shared__ float W[NW_TOT];
    const int lt = threadIdx.x;
    lds_copy(W + OFF_W0, w0, 32, lt);
    lds_copy(W + OFF_B0, b0, 16, lt);
    lds_copy(W + OFF_W1, w1, 512, lt);
    lds_copy(W + OFF_B1, b1, 32, lt);
    lds_copy(W + OFF_W2, w2, 1024, lt);
    lds_copy(W + OFF_B2, b2, 32, lt);
    lds_copy(W + OFF_W3, w3, 512, lt);
    lds_copy(W + OFF_B3, b3, 16, lt);
    lds_copy(W + OFF_W4, w4, 16, lt);
    __syncthreads();

    const int tid = blockIdx.x * 64 + lt;
    const int bi = tid / NCELLS;
    const int ci = tid - bi * NCELLS;
    const float* xr = x + bi * XROW;

    float y0 = xr[2 + ci * 2 + 0];
    float y1 = xr[2 + ci * 2 + 1];
    float ts = xr[0];
    const float sp0    = xr[XROW - 5];
    const float sg_lo0 = xr[XROW - 4], sg_lo1 = xr[XROW - 3];
    const float sg_hi0 = xr[XROW - 2], sg_hi1 = xr[XROW - 1];

    const float wt00 = wt[0], wt01 = wt[1], wt10 = wt[2], wt11 = wt[3];
    const float tl0 = sg_lo0 * wt00 + sg_lo1 * wt01;
    const float tl1 = sg_lo0 * wt10 + sg_lo1 * wt11;
    const float th0 = sg_hi0 * wt00 + sg_hi1 * wt01;
    const float th1 = sg_hi0 * wt10 + sg_hi1 * wt11;

    const int nsteps = (int)((x[1] - x[0]) / DT_F + 0.5f);

    #pragma unroll 1
    for (int it = 0; it < nsteps; ++it) {
        // Block LICM from hoisting the (loop-invariant) LDS weight reads out
        // of the time loop: barrier = LDS memory fence. Round-2 lesson: the
        // hoist spilled ~2000 floats to scratch -> 9.8 GB of HBM traffic.
        __syncthreads();
        asm volatile("" ::: "memory");

        const bool lo = ts < sp0;
        const float tilt0 = lo ? tl0 : th0;
        const float tilt1 = lo ? tl1 : th1;

        // ---------- forward ----------
        float a1[16];
        #pragma unroll
        for (int j = 0; j < 16; j += 2) {
            float4 wv = *(const float4*)&W[OFF_W0 + 2 * j];
            float z0 = fmaf(wv.x, y0, fmaf(wv.y, y1, W[OFF_B0 + j]));
            float z1 = fmaf(wv.z, y0, fmaf(wv.w, y1, W[OFF_B0 + j + 1]));
            a1[j] = softplus_f(z0);
            a1[j + 1] = softplus_f(z1);
        }
        float a2[32];
        #pragma unroll
        for (int j = 0; j < 32; j += 2) {
            float z0 = W[OFF_B1 + j];
            float z1 = W[OFF_B1 + j + 1];
            #pragma unroll
            for (int k = 0; k < 16; k += 4) {
                float4 wa = *(const float4*)&W[OFF_W1 + 16 * j + k];
                float4 wb = *(const float4*)&W[OFF_W1 + 16 * (j + 1) + k];
                z0 = fmaf(wa.x, a1[k], z0);
                z0 = fmaf(wa.y, a1[k + 1], z0);
                z0 = fmaf(wa.z, a1[k + 2], z0);
                z0 = fmaf(wa.w, a1[k + 3], z0);
                z1 = fmaf(wb.x, a1[k], z1);
                z1 = fmaf(wb.y, a1[k + 1], z1);
                z1 = fmaf(wb.z, a1[k + 2], z1);
                z1 = fmaf(wb.w, a1[k + 3], z1);
            }
            a2[j] = softplus_f(z0);
            a2[j + 1] = softplus_f(z1);
        }
        float a3[32];
        #pragma unroll
        for (int j = 0; j < 32; j += 2) {
            float z0 = W[OFF_B2 + j];
            float z1 = W[OFF_B2 + j + 1];
            #pragma unroll
            for (int k = 0; k < 32; k += 4) {
                float4 wa = *(const float4*)&W[OFF_W2 + 32 * j + k];
                float4 wb = *(const float4*)&W[OFF_W2 + 32 * (j + 1) + k];
                z0 = fmaf(wa.x, a2[k], z0);
                z0 = fmaf(wa.y, a2[k + 1], z0);
                z0 = fmaf(wa.z, a2[k + 2], z0);
                z0 = fmaf(wa.w, a2[k + 3], z0);
                z1 = fmaf(wb.x, a2[k], z1);
                z1 = fmaf(wb.y, a2[k + 1], z1);
                z1 = fmaf(wb.z, a2[k + 2], z1);
                z1 = fmaf(wb.w, a2[k + 3], z1);
            }
            a3[j] = softplus_f(z0);
            a3[j + 1] = softplus_f(z1);
        }
        float a4[16];
        #pragma unroll
        for (int j = 0; j < 16; j += 2) {
            float z0 = W[OFF_B3 + j];
            float z1 = W[OFF_B3 + j + 1];
            #pragma unroll
            for (int k = 0; k < 32; k += 4) {
                float4 wa = *(const float4*)&W[OFF_W3 + 32 * j + k];
                float4 wb = *(const float4*)&W[OFF_W3 + 32 * (j + 1) + k];
                z0 = fmaf(wa.x, a3[k], z0);
                z0 = fmaf(wa.y, a3[k + 1], z0);
                z0 = fmaf(wa.z, a3[k + 2], z0);
                z0 = fmaf(wa.w, a3[k + 3], z0);
                z1 = fmaf(wb.x, a3[k], z1);
                z1 = fmaf(wb.y, a3[k + 1], z1);
                z1 = fmaf(wb.z, a3[k + 2], z1);
                z1 = fmaf(wb.w, a3[k + 3], z1);
            }
            a4[j] = softplus_f(z0);
            a4[j + 1] = softplus_f(z1);
        }

        // ---------- backward:  sigma(z) = 1 - exp(-softplus(z)) ----------
        float g4[16];
        #pragma unroll
        for (int j = 0; j < 16; j += 4) {
            float4 wv = *(const float4*)&W[OFF_W4 + j];
            g4[j]     = wv.x * (1.0f - __expf(-a4[j]));
            g4[j + 1] = wv.y * (1.0f - __expf(-a4[j + 1]));
            g4[j + 2] = wv.z * (1.0f - __expf(-a4[j + 2]));
            g4[j + 3] = wv.w * (1.0f - __expf(-a4[j + 3]));
        }
        float g3[32];
        #pragma unroll
        for (int k = 0; k < 32; ++k) g3[k] = 0.0f;
        #pragma unroll
        for (int j = 0; j < 16; ++j) {
            const float gj = g4[j];
            #pragma unroll
            for (int k = 0; k < 32; k += 4) {
                float4 wv = *(const float4*)&W[OFF_W3 + 32 * j + k];
                g3[k]     = fmaf(wv.x, gj, g3[k]);
                g3[k + 1] = fmaf(wv.y, gj, g3[k + 1]);
                g3[k + 2] = fmaf(wv.z, gj, g3[k + 2]);
                g3[k + 3] = fmaf(wv.w, gj, g3[k + 3]);
            }
        }
        #pragma unroll
        for (int k = 0; k < 32; ++k) g3[k] *= (1.0f - __expf(-a3[k]));

        float g2[32];
        #pragma unroll
        for (int k = 0; k < 32; ++k) g2[k] = 0.0f;
        #pragma unroll
        for (int j = 0; j < 32; ++j) {
            const float gj = g3[j];
            #pragma unroll
            for (int k = 0; k < 32; k += 4) {
                float4 wv = *(const float4*)&W[OFF_W2 + 32 * j + k];
                g2[k]     = fmaf(wv.x, gj, g2[k]);
                g2[k + 1] = fmaf(wv.y, gj, g2[k + 1]);
                g2[k + 2] = fmaf(wv.z, gj, g2[k + 2]);
                g2[k + 3] = fmaf(wv.w, gj, g2[k + 3]);
            }
        }
        #pragma unroll
        for (int k = 0; k < 32; ++k) g2[k] *= (1.0f - __expf(-a2[k]));

        float g1[16];
        #pragma unroll
        for (int k = 0; k < 16; ++k) g1[k] = 0.0f;
        #pragma unroll
        for (int j = 0; j < 32; ++j) {
            const float gj = g2[j];
            #pragma unroll
            for (int k = 0; k < 16; k += 4) {
                float4 wv = *(const float4*)&W[OFF_W1 + 16 * j + k];
                g1[k]     = fmaf(wv.x, gj, g1[k]);
                g1[k + 1] = fmaf(wv.y, gj, g1[k + 1]);
                g1[k + 2] = fmaf(wv.z, gj, g1[k + 2]);
                g1[k + 3] = fmaf(wv.w, gj, g1[k + 3]);
            }
        }
        float gy0 = 0.0f, gy1 = 0.0f;
        #pragma unroll
        for (int j = 0; j < 16; j += 2) {
            float4 wv = *(const float4*)&W[OFF_W0 + 2 * j];
            const float s0 = g1[j]     * (1.0f - __expf(-a1[j]));
            const float s1 = g1[j + 1] * (1.0f - __expf(-a1[j + 1]));
            gy0 = fmaf(wv.x, s0, gy0);
            gy1 = fmaf(wv.y, s0, gy1);
            gy0 = fmaf(wv.z, s1, gy0);
            gy1 = fmaf(wv.w, s1, gy1);
        }

        y0 = fmaf(-(gy0 + tilt0), DT_F, y0);
        y1 = fmaf(-(gy1 + tilt1), DT_F, y1);
        ts += DT_F;
    }

    out[2 * tid + 0] = y0;
    out[2 * tid + 1] = y1;
}

extern "C" void kernel_launch(void* const* d_in, const int* in_sizes, int n_in,
                              void* d_out, int out_size, void* d_ws, size_t ws_size,
                              hipStream_t stream) {
    (void)in_sizes; (void)n_in; (void)d_ws; (void)ws_size; (void)out_size;
    const float* w0 = (const float*)d_in[0];
    const float* b0 = (const float*)d_in[1];
    const float* w1 = (const float*)d_in[2];
    const float* b1 = (const float*)d_in[3];
    const float* w2 = (const float*)d_in[4];
    const float* b2 = (const float*)d_in[5];
    const float* w3 = (const float*)d_in[6];
    const float* b3 = (const float*)d_in[7];
    const float* w4 = (const float*)d_in[8];
    const float* b4 = (const float*)d_in[9];
    const float* wt = (const float*)d_in[10];
    const float* x  = (const float*)d_in[11];
    float* out = (float*)d_out;

    dim3 grid(NPTS / 64), block(64);
    hipLaunchKernelGGL(phinn_kernel, grid, block, 0, stream,
                       w0, b0, w1, b1, w2, b2, w3, b3, w4, b4, wt, x, out);
}

// Round 4
// 621.192 us; speedup vs baseline: 35.5614x; 16.5723x over previous
//
#include <hip/hip_runtime.h>

#define NDIM 2
#define NCELLS 200
#define BATCH 128
#define NPTS (BATCH * NCELLS)
#define NTHREADS (NPTS * 4)   /* 4 lanes per point */
#define XROW (2 + NCELLS * NDIM + 5) /* 407 */
#define DT_F 0.001f

// LDS float offsets (all 16B-aligned)
#define OFF_W0 0      /* 16x2  = 32  */
#define OFF_B0 32     /* 16  */
#define OFF_W1 48     /* 32x16 = 512 */
#define OFF_B1 560    /* 32  */
#define OFF_W2 592    /* 32x32 = 1024 */
#define OFF_B2 1616   /* 32  */
#define OFF_W3 1648   /* 16x32 = 512 */
#define OFF_B3 2160   /* 16  */
#define OFF_W4 2176   /* 16  */
#define NW_TOT 2192

// ds_swizzle BitMode imms: src_lane = ((lane & and) | or) ^ xor  (per 32-half)
// quad broadcast of sublane t: and=0x1C, or=t
#define QB0 ((0 << 5) | 0x1C)
#define QB1 ((1 << 5) | 0x1C)
#define QB2 ((2 << 5) | 0x1C)
#define QB3 ((3 << 5) | 0x1C)
// quad butterfly xor 1 / 2
#define QX1 ((1 << 10) | 0x1F)
#define QX2 ((2 << 10) | 0x1F)

template <int IMM>
__device__ __forceinline__ float swz(float v) {
    return __int_as_float(__builtin_amdgcn_ds_swizzle(__float_as_int(v), IMM));
}

// full[t*N+i] = own[i] of sublane t   (quad gather via static swizzles)
template <int N>
__device__ __forceinline__ void gather4(float* full, const float* own) {
#pragma unroll
    for (int i = 0; i < N; ++i) {
        full[0 * N + i] = swz<QB0>(own[i]);
        full[1 * N + i] = swz<QB1>(own[i]);
        full[2 * N + i] = swz<QB2>(own[i]);
        full[3 * N + i] = swz<QB3>(own[i]);
    }
}

__device__ __forceinline__ float softplus_f(float z) {
    float e = __expf(-fabsf(z));
    return fmaxf(z, 0.0f) + __logf(1.0f + e);
}

__device__ __forceinline__ void lds_copy(float* dst, const float* src, int n, int tid) {
    for (int i = tid; i < n; i += 64) dst[i] = src[i];
}

#define FENCE() asm volatile("" ::: "memory")

__global__ void __launch_bounds__(64, 4) phinn_kernel(
    const float* __restrict__ w0, const float* __restrict__ b0,
    const float* __restrict__ w1, const float* __restrict__ b1,
    const float* __restrict__ w2, const float* __restrict__ b2,
    const float* __restrict__ w3, const float* __restrict__ b3,
    const float* __restrict__ w4, const float* __restrict__ b4,
    const float* __restrict__ wt, const float* __restrict__ x,
    float* __restrict__ out)
{
    __shared__ float W[NW_TOT];
    const int lt = threadIdx.x;
    lds_copy(W + OFF_W0, w0, 32, lt);
    lds_copy(W + OFF_B0, b0, 16, lt);
    lds_copy(W + OFF_W1, w1, 512, lt);
    lds_copy(W + OFF_B1, b1, 32, lt);
    lds_copy(W + OFF_W2, w2, 1024, lt);
    lds_copy(W + OFF_B2, b2, 32, lt);
    lds_copy(W + OFF_W3, w3, 512, lt);
    lds_copy(W + OFF_B3, b3, 16, lt);
    lds_copy(W + OFF_W4, w4, 16, lt);
    __syncthreads();

    const int gtid = blockIdx.x * 64 + lt;
    const int p = gtid >> 2;      // point index
    const int s = lt & 3;         // sublane within quad
    const int s4 = s * 4, s8 = s * 8;
    const int bi = p / NCELLS;
    const int ci = p - bi * NCELLS;
    const float* xr = x + bi * XROW;

    float y0 = xr[2 + 2 * ci];
    float y1 = xr[3 + 2 * ci];
    float ts = xr[0];
    const float sp0    = xr[XROW - 5];
    const float sg_lo0 = xr[XROW - 4], sg_lo1 = xr[XROW - 3];
    const float sg_hi0 = xr[XROW - 2], sg_hi1 = xr[XROW - 1];

    const float wt00 = wt[0], wt01 = wt[1], wt10 = wt[2], wt11 = wt[3];
    const float tl0 = sg_lo0 * wt00 + sg_lo1 * wt01;
    const float tl1 = sg_lo0 * wt10 + sg_lo1 * wt11;
    const float th0 = sg_hi0 * wt00 + sg_hi1 * wt01;
    const float th1 = sg_hi0 * wt10 + sg_hi1 * wt11;

    const int nsteps = (int)((x[1] - x[0]) / DT_F + 0.5f);

    #pragma unroll 1
    for (int it = 0; it < nsteps; ++it) {
        __syncthreads();   // LDS fence: forbid hoisting weight reads across steps
        FENCE();

        const bool lo = ts < sp0;
        const float tilt0 = lo ? tl0 : th0;
        const float tilt1 = lo ? tl1 : th1;

        // ---------------- forward ----------------
        // L1: own neurons j in [s4, s4+4)
        float a1o[4];
        {
            float4 wa = *(const float4*)&W[OFF_W0 + 2 * s4];
            float4 wb = *(const float4*)&W[OFF_W0 + 2 * s4 + 4];
            a1o[0] = softplus_f(fmaf(wa.x, y0, fmaf(wa.y, y1, W[OFF_B0 + s4 + 0])));
            a1o[1] = softplus_f(fmaf(wa.z, y0, fmaf(wa.w, y1, W[OFF_B0 + s4 + 1])));
            a1o[2] = softplus_f(fmaf(wb.x, y0, fmaf(wb.y, y1, W[OFF_B0 + s4 + 2])));
            a1o[3] = softplus_f(fmaf(wb.z, y0, fmaf(wb.w, y1, W[OFF_B0 + s4 + 3])));
        }
        float a1f[16];
        gather4<4>(a1f, a1o);
        FENCE();

        // L2: own neurons j in [s8, s8+8), w1 rows (16 wide)
        float a2o[8];
        #pragma unroll
        for (int jj = 0; jj < 8; ++jj) {
            const int j = s8 + jj;
            float z = W[OFF_B1 + j];
            #pragma unroll
            for (int k = 0; k < 16; k += 4) {
                float4 wv = *(const float4*)&W[OFF_W1 + 16 * j + k];
                z = fmaf(wv.x, a1f[k], z);
                z = fmaf(wv.y, a1f[k + 1], z);
                z = fmaf(wv.z, a1f[k + 2], z);
                z = fmaf(wv.w, a1f[k + 3], z);
            }
            a2o[jj] = softplus_f(z);
            if ((jj & 3) == 3) FENCE();
        }
        float a2f[32];
        gather4<8>(a2f, a2o);
        FENCE();

        // L3: own neurons j in [s8, s8+8), w2 rows (32 wide)
        float a3o[8];
        #pragma unroll
        for (int jj = 0; jj < 8; ++jj) {
            const int j = s8 + jj;
            float z = W[OFF_B2 + j];
            #pragma unroll
            for (int k = 0; k < 32; k += 4) {
                float4 wv = *(const float4*)&W[OFF_W2 + 32 * j + k];
                z = fmaf(wv.x, a2f[k], z);
                z = fmaf(wv.y, a2f[k + 1], z);
                z = fmaf(wv.z, a2f[k + 2], z);
                z = fmaf(wv.w, a2f[k + 3], z);
            }
            a3o[jj] = softplus_f(z);
            if ((jj & 1) == 1) FENCE();
        }
        float a3f[32];
        gather4<8>(a3f, a3o);
        FENCE();

        // L4: own neurons j in [s4, s4+4), w3 rows (32 wide)
        float a4o[4];
        #pragma unroll
        for (int jj = 0; jj < 4; ++jj) {
            const int j = s4 + jj;
            float z = W[OFF_B3 + j];
            #pragma unroll
            for (int k = 0; k < 32; k += 4) {
                float4 wv = *(const float4*)&W[OFF_W3 + 32 * j + k];
                z = fmaf(wv.x, a3f[k], z);
                z = fmaf(wv.y, a3f[k + 1], z);
                z = fmaf(wv.z, a3f[k + 2], z);
                z = fmaf(wv.w, a3f[k + 3], z);
            }
            a4o[jj] = softplus_f(z);
            if ((jj & 1) == 1) FENCE();
        }

        // ---------------- backward:  sigma' = 1 - exp(-a) ----------------
        float g4o[4];
        {
            float4 wv = *(const float4*)&W[OFF_W4 + s4];
            g4o[0] = wv.x * (1.0f - __expf(-a4o[0]));
            g4o[1] = wv.y * (1.0f - __expf(-a4o[1]));
            g4o[2] = wv.z * (1.0f - __expf(-a4o[2]));
            g4o[3] = wv.w * (1.0f - __expf(-a4o[3]));
        }
        float g4f[16];
        gather4<4>(g4f, g4o);
        FENCE();

        // g3: own cols k in [s8, s8+8) of w3 (16 rows x 32)
        float g3o[8] = {0, 0, 0, 0, 0, 0, 0, 0};
        #pragma unroll
        for (int j = 0; j < 16; ++j) {
            const float gj = g4f[j];
            float4 wa = *(const float4*)&W[OFF_W3 + 32 * j + s8];
            float4 wb = *(const float4*)&W[OFF_W3 + 32 * j + s8 + 4];
            g3o[0] = fmaf(wa.x, gj, g3o[0]);
            g3o[1] = fmaf(wa.y, gj, g3o[1]);
            g3o[2] = fmaf(wa.z, gj, g3o[2]);
            g3o[3] = fmaf(wa.w, gj, g3o[3]);
            g3o[4] = fmaf(wb.x, gj, g3o[4]);
            g3o[5] = fmaf(wb.y, gj, g3o[5]);
            g3o[6] = fmaf(wb.z, gj, g3o[6]);
            g3o[7] = fmaf(wb.w, gj, g3o[7]);
            if ((j & 3) == 3) FENCE();
        }
        #pragma unroll
        for (int kk = 0; kk < 8; ++kk) g3o[kk] *= (1.0f - __expf(-a3o[kk]));
        float g3f[32];
        gather4<8>(g3f, g3o);
        FENCE();

        // g2: own cols k in [s8, s8+8) of w2 (32 rows x 32)
        float g2o[8] = {0, 0, 0, 0, 0, 0, 0, 0};
        #pragma unroll
        for (int j = 0; j < 32; ++j) {
            const float gj = g3f[j];
            float4 wa = *(const float4*)&W[OFF_W2 + 32 * j + s8];
            float4 wb = *(const float4*)&W[OFF_W2 + 32 * j + s8 + 4];
            g2o[0] = fmaf(wa.x, gj, g2o[0]);
            g2o[1] = fmaf(wa.y, gj, g2o[1]);
            g2o[2] = fmaf(wa.z, gj, g2o[2]);
            g2o[3] = fmaf(wa.w, gj, g2o[3]);
            g2o[4] = fmaf(wb.x, gj, g2o[4]);
            g2o[5] = fmaf(wb.y, gj, g2o[5]);
            g2o[6] = fmaf(wb.z, gj, g2o[6]);
            g2o[7] = fmaf(wb.w, gj, g2o[7]);
            if ((j & 3) == 3) FENCE();
        }
        #pragma unroll
        for (int kk = 0; kk < 8; ++kk) g2o[kk] *= (1.0f - __expf(-a2o[kk]));
        float g2f[32];
        gather4<8>(g2f, g2o);
        FENCE();

        // g1: own cols k in [s4, s4+4) of w1 (32 rows x 16)
        float g1o[4] = {0, 0, 0, 0};
        #pragma unroll
        for (int j = 0; j < 32; ++j) {
            const float gj = g2f[j];
            float4 wv = *(const float4*)&W[OFF_W1 + 16 * j + s4];
            g1o[0] = fmaf(wv.x, gj, g1o[0]);
            g1o[1] = fmaf(wv.y, gj, g1o[1]);
            g1o[2] = fmaf(wv.z, gj, g1o[2]);
            g1o[3] = fmaf(wv.w, gj, g1o[3]);
            if ((j & 3) == 3) FENCE();
        }
        #pragma unroll
        for (int kk = 0; kk < 4; ++kk) g1o[kk] *= (1.0f - __expf(-a1o[kk]));

        // gy partial over own rows j in [s4, s4+4) of w0, then quad butterfly
        float gy0, gy1;
        {
            float4 wa = *(const float4*)&W[OFF_W0 + 2 * s4];
            float4 wb = *(const float4*)&W[OFF_W0 + 2 * s4 + 4];
            gy0 = wa.x * g1o[0] + wa.z * g1o[1] + wb.x * g1o[2] + wb.z * g1o[3];
            gy1 = wa.y * g1o[0] + wa.w * g1o[1] + wb.y * g1o[2] + wb.w * g1o[3];
        }
        gy0 += swz<QX1>(gy0);
        gy0 += swz<QX2>(gy0);
        gy1 += swz<QX1>(gy1);
        gy1 += swz<QX2>(gy1);

        y0 = fmaf(-(gy0 + tilt0), DT_F, y0);
        y1 = fmaf(-(gy1 + tilt1), DT_F, y1);
        ts += DT_F;
    }

    if (s == 0) {
        out[2 * p + 0] = y0;
        out[2 * p + 1] = y1;
    }
}

extern "C" void kernel_launch(void* const* d_in, const int* in_sizes, int n_in,
                              void* d_out, int out_size, void* d_ws, size_t ws_size,
                              hipStream_t stream) {
    (void)in_sizes; (void)n_in; (void)d_ws; (void)ws_size; (void)out_size;
    const float* w0 = (const float*)d_in[0];
    const float* b0 = (const float*)d_in[1];
    const float* w1 = (const float*)d_in[2];
    const float* b1 = (const float*)d_in[3];
    const float* w2 = (const float*)d_in[4];
    const float* b2 = (const float*)d_in[5];
    const float* w3 = (const float*)d_in[6];
    const float* b3 = (const float*)d_in[7];
    const float* w4 = (const float*)d_in[8];
    const float* b4 = (const float*)d_in[9];
    const float* wt = (const float*)d_in[10];
    const float* x  = (const float*)d_in[11];
    float* out = (float*)d_out;

    dim3 grid(NTHREADS / 64), block(64);
    hipLaunchKernelGGL(phinn_kernel, grid, block, 0, stream,
                       w0, b0, w1, b1, w2, b2, w3, b3, w4, b4, wt, x, out);
}

// Round 5
// 495.763 us; speedup vs baseline: 44.5585x; 1.2530x over previous
//
#include <hip/hip_runtime.h>

#define NDIM 2
#define NCELLS 200
#define BATCH 128
#define NPTS (BATCH * NCELLS)
#define NTHREADS (NPTS * 4)   /* 4 lanes per point */
#define XROW (2 + NCELLS * NDIM + 5) /* 407 */
#define DT_F 0.001f

// ---- LDS layout with anti-conflict gaps ----
// W1 rows of 16 floats, +4-float gap every 8 rows  -> base 16j + 4(j>>3)
// W2 rows of 32 floats, +4-float gap every 8 rows  -> base 32j + 4(j>>3)
// W3 rows of 32 floats, +4-float gap every 4 rows  -> base 32j + 4(j>>2)
// S-group bases then differ by 132/260/132 floats -> banks 4s apart (distinct),
// instead of multiples of 128/256 floats (all same bank -> 4-way conflict).
#define OFF_W0 0      /* 32  */
#define OFF_B0 32     /* 16  */
#define OFF_W1 48     /* 524 -> reserve 528 */
#define OFF_B1 576    /* 32  */
#define OFF_W2 608    /* 1036 -> reserve 1040 */
#define OFF_B2 1648   /* 32  */
#define OFF_W3 1680   /* 524 -> reserve 528 */
#define OFF_B3 2208   /* 16  */
#define OFF_W4 2224   /* 16  */
#define NW_TOT 2240

#define W1BASE(j) (16 * (j) + 4 * ((j) >> 3))
#define W2BASE(j) (32 * (j) + 4 * ((j) >> 3))
#define W3BASE(j) (32 * (j) + 4 * ((j) >> 2))

// ds_swizzle BitMode imms: src_lane = ((lane & and) | or) ^ xor  (per 32-half)
#define QB0 ((0 << 5) | 0x1C)
#define QB1 ((1 << 5) | 0x1C)
#define QB2 ((2 << 5) | 0x1C)
#define QB3 ((3 << 5) | 0x1C)
#define QX1 ((1 << 10) | 0x1F)
#define QX2 ((2 << 10) | 0x1F)

template <int IMM>
__device__ __forceinline__ float swz(float v) {
    return __int_as_float(__builtin_amdgcn_ds_swizzle(__float_as_int(v), IMM));
}

template <int N>
__device__ __forceinline__ void gather4(float* full, const float* own) {
#pragma unroll
    for (int i = 0; i < N; ++i) {
        full[0 * N + i] = swz<QB0>(own[i]);
        full[1 * N + i] = swz<QB1>(own[i]);
        full[2 * N + i] = swz<QB2>(own[i]);
        full[3 * N + i] = swz<QB3>(own[i]);
    }
}

__device__ __forceinline__ float softplus_f(float z) {
    float e = __expf(-fabsf(z));
    return fmaxf(z, 0.0f) + __logf(1.0f + e);
}

#define FENCE() asm volatile("" ::: "memory")

__global__ void __launch_bounds__(64, 4) phinn_kernel(
    const float* __restrict__ w0, const float* __restrict__ b0,
    const float* __restrict__ w1, const float* __restrict__ b1,
    const float* __restrict__ w2, const float* __restrict__ b2,
    const float* __restrict__ w3, const float* __restrict__ b3,
    const float* __restrict__ w4, const float* __restrict__ b4,
    const float* __restrict__ wt, const float* __restrict__ x,
    float* __restrict__ out)
{
    __shared__ float W[NW_TOT];
    const int lt = threadIdx.x;
    // staging with padded scatter (once per block)
    for (int i = lt; i < 32; i += 64)  W[OFF_W0 + i] = w0[i];
    for (int i = lt; i < 16; i += 64)  W[OFF_B0 + i] = b0[i];
    for (int i = lt; i < 512; i += 64) W[OFF_W1 + W1BASE(i >> 4) + (i & 15)] = w1[i];
    for (int i = lt; i < 32; i += 64)  W[OFF_B1 + i] = b1[i];
    for (int i = lt; i < 1024; i += 64) W[OFF_W2 + W2BASE(i >> 5) + (i & 31)] = w2[i];
    for (int i = lt; i < 32; i += 64)  W[OFF_B2 + i] = b2[i];
    for (int i = lt; i < 512; i += 64) W[OFF_W3 + W3BASE(i >> 5) + (i & 31)] = w3[i];
    for (int i = lt; i < 16; i += 64)  W[OFF_B3 + i] = b3[i];
    for (int i = lt; i < 16; i += 64)  W[OFF_W4 + i] = w4[i];
    __syncthreads();

    const int gtid = blockIdx.x * 64 + lt;
    const int p = gtid >> 2;      // point index
    const int s = lt & 3;         // sublane within quad
    const int s4 = s * 4, s8 = s * 8;
    const int bi = p / NCELLS;
    const int ci = p - bi * NCELLS;
    const float* xr = x + bi * XROW;

    float y0 = xr[2 + 2 * ci];
    float y1 = xr[3 + 2 * ci];
    float ts = xr[0];
    const float sp0    = xr[XROW - 5];
    const float sg_lo0 = xr[XROW - 4], sg_lo1 = xr[XROW - 3];
    const float sg_hi0 = xr[XROW - 2], sg_hi1 = xr[XROW - 1];

    const float wt00 = wt[0], wt01 = wt[1], wt10 = wt[2], wt11 = wt[3];
    const float tl0 = sg_lo0 * wt00 + sg_lo1 * wt01;
    const float tl1 = sg_lo0 * wt10 + sg_lo1 * wt11;
    const float th0 = sg_hi0 * wt00 + sg_hi1 * wt01;
    const float th1 = sg_hi0 * wt10 + sg_hi1 * wt11;

    const int nsteps = (int)((x[1] - x[0]) / DT_F + 0.5f);

    // per-s forward base pointers (rows j = s*8+jj or s*4+jj)
    const int w1f = OFF_W1 + 132 * s;   // + 16*jj
    const int w2f = OFF_W2 + 260 * s;   // + 32*jj
    const int w3f = OFF_W3 + 132 * s;   // + 32*jj

    #pragma unroll 1
    for (int it = 0; it < nsteps; ++it) {
        __syncthreads();   // LDS fence: forbid hoisting weight reads across steps
        FENCE();

        const bool lo = ts < sp0;
        const float tilt0 = lo ? tl0 : th0;
        const float tilt1 = lo ? tl1 : th1;

        // ---------------- forward ----------------
        float a1o[4];
        {
            float4 wa = *(const float4*)&W[OFF_W0 + 2 * s4];
            float4 wb = *(const float4*)&W[OFF_W0 + 2 * s4 + 4];
            a1o[0] = softplus_f(fmaf(wa.x, y0, fmaf(wa.y, y1, W[OFF_B0 + s4 + 0])));
            a1o[1] = softplus_f(fmaf(wa.z, y0, fmaf(wa.w, y1, W[OFF_B0 + s4 + 1])));
            a1o[2] = softplus_f(fmaf(wb.x, y0, fmaf(wb.y, y1, W[OFF_B0 + s4 + 2])));
            a1o[3] = softplus_f(fmaf(wb.z, y0, fmaf(wb.w, y1, W[OFF_B0 + s4 + 3])));
        }
        float a1f[16];
        gather4<4>(a1f, a1o);
        FENCE();

        // L2: own neurons j in [s8, s8+8)
        float a2o[8];
        #pragma unroll
        for (int jj = 0; jj < 8; ++jj) {
            float z = W[OFF_B1 + s8 + jj];
            #pragma unroll
            for (int k = 0; k < 16; k += 4) {
                float4 wv = *(const float4*)&W[w1f + 16 * jj + k];
                z = fmaf(wv.x, a1f[k], z);
                z = fmaf(wv.y, a1f[k + 1], z);
                z = fmaf(wv.z, a1f[k + 2], z);
                z = fmaf(wv.w, a1f[k + 3], z);
            }
            a2o[jj] = softplus_f(z);
            if ((jj & 3) == 3) FENCE();
        }
        float a2f[32];
        gather4<8>(a2f, a2o);
        FENCE();

        // L3: own neurons j in [s8, s8+8)
        float a3o[8];
        #pragma unroll
        for (int jj = 0; jj < 8; ++jj) {
            float z = W[OFF_B2 + s8 + jj];
            #pragma unroll
            for (int k = 0; k < 32; k += 4) {
                float4 wv = *(const float4*)&W[w2f + 32 * jj + k];
                z = fmaf(wv.x, a2f[k], z);
                z = fmaf(wv.y, a2f[k + 1], z);
                z = fmaf(wv.z, a2f[k + 2], z);
                z = fmaf(wv.w, a2f[k + 3], z);
            }
            a3o[jj] = softplus_f(z);
            if ((jj & 1) == 1) FENCE();
        }
        float a3f[32];
        gather4<8>(a3f, a3o);
        FENCE();

        // L4: own neurons j in [s4, s4+4)
        float a4o[4];
        #pragma unroll
        for (int jj = 0; jj < 4; ++jj) {
            float z = W[OFF_B3 + s4 + jj];
            #pragma unroll
            for (int k = 0; k < 32; k += 4) {
                float4 wv = *(const float4*)&W[w3f + 32 * jj + k];
                z = fmaf(wv.x, a3f[k], z);
                z = fmaf(wv.y, a3f[k + 1], z);
                z = fmaf(wv.z, a3f[k + 2], z);
                z = fmaf(wv.w, a3f[k + 3], z);
            }
            a4o[jj] = softplus_f(z);
            if ((jj & 1) == 1) FENCE();
        }

        // ---------------- backward:  sigma' = 1 - exp(-a) ----------------
        float g4o[4];
        {
            float4 wv = *(const float4*)&W[OFF_W4 + s4];
            g4o[0] = wv.x * (1.0f - __expf(-a4o[0]));
            g4o[1] = wv.y * (1.0f - __expf(-a4o[1]));
            g4o[2] = wv.z * (1.0f - __expf(-a4o[2]));
            g4o[3] = wv.w * (1.0f - __expf(-a4o[3]));
        }
        float g4f[16];
        gather4<4>(g4f, g4o);
        FENCE();

        // g3: own cols k in [s8, s8+8) of w3 (16 rows x 32)
        float g3o[8] = {0, 0, 0, 0, 0, 0, 0, 0};
        #pragma unroll
        for (int j = 0; j < 16; ++j) {
            const float gj = g4f[j];
            float4 wa = *(const float4*)&W[OFF_W3 + W3BASE(j) + s8];
            float4 wb = *(const float4*)&W[OFF_W3 + W3BASE(j) + s8 + 4];
            g3o[0] = fmaf(wa.x, gj, g3o[0]);
            g3o[1] = fmaf(wa.y, gj, g3o[1]);
            g3o[2] = fmaf(wa.z, gj, g3o[2]);
            g3o[3] = fmaf(wa.w, gj, g3o[3]);
            g3o[4] = fmaf(wb.x, gj, g3o[4]);
            g3o[5] = fmaf(wb.y, gj, g3o[5]);
            g3o[6] = fmaf(wb.z, gj, g3o[6]);
            g3o[7] = fmaf(wb.w, gj, g3o[7]);
            if ((j & 3) == 3) FENCE();
        }
        #pragma unroll
        for (int kk = 0; kk < 8; ++kk) g3o[kk] *= (1.0f - __expf(-a3o[kk]));
        float g3f[32];
        gather4<8>(g3f, g3o);
        FENCE();

        // g2: own cols k in [s8, s8+8) of w2 (32 rows x 32)
        float g2o[8] = {0, 0, 0, 0, 0, 0, 0, 0};
        #pragma unroll
        for (int j = 0; j < 32; ++j) {
            const float gj = g3f[j];
            float4 wa = *(const float4*)&W[OFF_W2 + W2BASE(j) + s8];
            float4 wb = *(const float4*)&W[OFF_W2 + W2BASE(j) + s8 + 4];
            g2o[0] = fmaf(wa.x, gj, g2o[0]);
            g2o[1] = fmaf(wa.y, gj, g2o[1]);
            g2o[2] = fmaf(wa.z, gj, g2o[2]);
            g2o[3] = fmaf(wa.w, gj, g2o[3]);
            g2o[4] = fmaf(wb.x, gj, g2o[4]);
            g2o[5] = fmaf(wb.y, gj, g2o[5]);
            g2o[6] = fmaf(wb.z, gj, g2o[6]);
            g2o[7] = fmaf(wb.w, gj, g2o[7]);
            if ((j & 3) == 3) FENCE();
        }
        #pragma unroll
        for (int kk = 0; kk < 8; ++kk) g2o[kk] *= (1.0f - __expf(-a2o[kk]));
        float g2f[32];
        gather4<8>(g2f, g2o);
        FENCE();

        // g1: own cols k in [s4, s4+4) of w1 (32 rows x 16)
        float g1o[4] = {0, 0, 0, 0};
        #pragma unroll
        for (int j = 0; j < 32; ++j) {
            const float gj = g2f[j];
            float4 wv = *(const float4*)&W[OFF_W1 + W1BASE(j) + s4];
            g1o[0] = fmaf(wv.x, gj, g1o[0]);
            g1o[1] = fmaf(wv.y, gj, g1o[1]);
            g1o[2] = fmaf(wv.z, gj, g1o[2]);
            g1o[3] = fmaf(wv.w, gj, g1o[3]);
            if ((j & 3) == 3) FENCE();
        }
        #pragma unroll
        for (int kk = 0; kk < 4; ++kk) g1o[kk] *= (1.0f - __expf(-a1o[kk]));

        // gy partial over own rows j in [s4, s4+4) of w0, then quad butterfly
        float gy0, gy1;
        {
            float4 wa = *(const float4*)&W[OFF_W0 + 2 * s4];
            float4 wb = *(const float4*)&W[OFF_W0 + 2 * s4 + 4];
            gy0 = wa.x * g1o[0] + wa.z * g1o[1] + wb.x * g1o[2] + wb.z * g1o[3];
            gy1 = wa.y * g1o[0] + wa.w * g1o[1] + wb.y * g1o[2] + wb.w * g1o[3];
        }
        gy0 += swz<QX1>(gy0);
        gy0 += swz<QX2>(gy0);
        gy1 += swz<QX1>(gy1);
        gy1 += swz<QX2>(gy1);

        y0 = fmaf(-(gy0 + tilt0), DT_F, y0);
        y1 = fmaf(-(gy1 + tilt1), DT_F, y1);
        ts += DT_F;
    }

    if (s == 0) {
        out[2 * p + 0] = y0;
        out[2 * p + 1] = y1;
    }
}

extern "C" void kernel_launch(void* const* d_in, const int* in_sizes, int n_in,
                              void* d_out, int out_size, void* d_ws, size_t ws_size,
                              hipStream_t stream) {
    (void)in_sizes; (void)n_in; (void)d_ws; (void)ws_size; (void)out_size;
    const float* w0 = (const float*)d_in[0];
    const float* b0 = (const float*)d_in[1];
    const float* w1 = (const float*)d_in[2];
    const float* b1 = (const float*)d_in[3];
    const float* w2 = (const float*)d_in[4];
    const float* b2 = (const float*)d_in[5];
    const float* w3 = (const float*)d_in[6];
    const float* b3 = (const float*)d_in[7];
    const float* w4 = (const float*)d_in[8];
    const float* b4 = (const float*)d_in[9];
    const float* wt = (const float*)d_in[10];
    const float* x  = (const float*)d_in[11];
    float* out = (float*)d_out;

    dim3 grid(NTHREADS / 64), block(64);
    hipLaunchKernelGGL(phinn_kernel, grid, block, 0, stream,
                       w0, b0, w1, b1, w2, b2, w3, b3, w4, b4, wt, x, out);
}

// Round 6
// 193.400 us; speedup vs baseline: 114.2217x; 2.5634x over previous
//
#include <hip/hip_runtime.h>

#define NDIM 2
#define NCELLS 200
#define BATCH 128
#define NPTS (BATCH * NCELLS)      /* 25600 */
#define NWAVES (NPTS / 16)         /* 1600: 16 points per wave */
#define XROW (2 + NCELLS * NDIM + 5) /* 407 */
#define DT_F 0.001f

typedef _Float16 v4h __attribute__((ext_vector_type(4)));
typedef float    v4f __attribute__((ext_vector_type(4)));

#define MFMA16(A, B, C) __builtin_amdgcn_mfma_f32_16x16x16f16((A), (B), (C), 0, 0, 0)

__device__ __forceinline__ float softplus_f(float z) {
    float e = __expf(-fabsf(z));
    return fmaxf(z, 0.0f) + __logf(1.0f + e);
}

// Layout facts used (m89-verified family, 16x16x16 f16):
//   A[m][k]: m = lane&15, k = (lane>>4)*4 + i   (i = vector elem 0..3)
//   B[k][n]: n = lane&15, k = (lane>>4)*4 + i
//   C/D[m][n]: n = lane&15, m = (lane>>4)*4 + reg
// => D of one layer is bit-for-bit in B-layout for the next layer (rows=k).
//    The entire fwd+bwd chain needs NO cross-lane exchange and NO LDS.

__global__ void __launch_bounds__(64, 2) phinn_kernel(
    const float* __restrict__ w0, const float* __restrict__ b0,
    const float* __restrict__ w1, const float* __restrict__ b1,
    const float* __restrict__ w2, const float* __restrict__ b2,
    const float* __restrict__ w3, const float* __restrict__ b3,
    const float* __restrict__ w4, const float* __restrict__ b4,
    const float* __restrict__ wt, const float* __restrict__ x,
    float* __restrict__ out)
{
    const int lane = threadIdx.x;     // 1 wave per block
    const int g = lane >> 4;          // k-group 0..3
    const int m = lane & 15;          // row (A) / col (B,C/D) index
    const int p = blockIdx.x * 16 + m;  // this lane's point (replicated over g)

    // ---------- one-time weight fragment preload (registers, f16) ----------
    v4h fW0, fW0T, fW1[2], fW1T[2], fW2[2][2], fW2T[2][2], fW3[2], fW3T[2];
    #pragma unroll
    for (int i = 0; i < 4; ++i) {
        const int k = 4 * g + i;
        // forward
        fW0[i] = (k < 2) ? (_Float16)w0[m * 2 + k] : (_Float16)0.f;
        #pragma unroll
        for (int t = 0; t < 2; ++t) {
            fW1[t][i]  = (_Float16)w1[(16 * t + m) * 16 + k];
            fW3[t][i]  = (_Float16)w3[m * 32 + 16 * t + k];
            fW1T[t][i] = (_Float16)w1[(16 * t + k) * 16 + m];
            fW3T[t][i] = (_Float16)w3[k * 32 + 16 * t + m];
            #pragma unroll
            for (int u = 0; u < 2; ++u) {
                fW2[t][u][i]  = (_Float16)w2[(16 * t + m) * 32 + 16 * u + k];
                fW2T[t][u][i] = (_Float16)w2[(16 * u + k) * 32 + 16 * t + m];
            }
        }
        fW0T[i] = (m < 2) ? (_Float16)w0[k * 2 + m] : (_Float16)0.f;
    }
    // biases / w4, per-lane slices (row = 4g + r)
    float b0v[4], b1v[8], b2v[8], b3v[4], w4v[4];
    #pragma unroll
    for (int r = 0; r < 4; ++r) {
        b0v[r] = b0[4 * g + r];
        b1v[r] = b1[4 * g + r];      b1v[4 + r] = b1[16 + 4 * g + r];
        b2v[r] = b2[4 * g + r];      b2v[4 + r] = b2[16 + 4 * g + r];
        b3v[r] = b3[4 * g + r];
        w4v[r] = w4[4 * g + r];
    }

    // ---------- per-point state ----------
    const int bi = p / NCELLS;
    const int ci = p - bi * NCELLS;
    const float* xr = x + bi * XROW;
    float y0 = xr[2 + 2 * ci];
    float y1 = xr[3 + 2 * ci];
    float ts = xr[0];
    const float sp0    = xr[XROW - 5];
    const float sg_lo0 = xr[XROW - 4], sg_lo1 = xr[XROW - 3];
    const float sg_hi0 = xr[XROW - 2], sg_hi1 = xr[XROW - 1];
    const float wt00 = wt[0], wt01 = wt[1], wt10 = wt[2], wt11 = wt[3];
    const float tl0 = sg_lo0 * wt00 + sg_lo1 * wt01;
    const float tl1 = sg_lo0 * wt10 + sg_lo1 * wt11;
    const float th0 = sg_hi0 * wt00 + sg_hi1 * wt01;
    const float th1 = sg_hi0 * wt10 + sg_hi1 * wt11;

    const int nsteps = (int)((x[1] - x[0]) / DT_F + 0.5f);
    const v4f zf = {0.f, 0.f, 0.f, 0.f};

    // Y fragment (B-layout): k=0 -> y0, k=1 -> y1, rest 0. Only g==0 nonzero.
    v4h fY;
    fY[0] = (g == 0) ? (_Float16)y0 : (_Float16)0.f;
    fY[1] = (g == 0) ? (_Float16)y1 : (_Float16)0.f;
    fY[2] = (_Float16)0.f; fY[3] = (_Float16)0.f;

    #pragma unroll 1
    for (int it = 0; it < nsteps; ++it) {
        const bool lo = ts < sp0;
        const float tilt0 = lo ? tl0 : th0;
        const float tilt1 = lo ? tl1 : th1;

        // ---- L1: z1 = W0*y + b0 ----
        v4f c = {b0v[0], b0v[1], b0v[2], b0v[3]};
        c = MFMA16(fW0, fY, c);
        v4h a1h; float sp1[4];
        #pragma unroll
        for (int i = 0; i < 4; ++i) {
            float a = softplus_f(c[i]);
            sp1[i] = 1.0f - __expf(-a);
            a1h[i] = (_Float16)a;
        }
        // ---- L2: 32 = W1(32x16)*a1 + b1 ----
        v4f c0 = {b1v[0], b1v[1], b1v[2], b1v[3]};
        v4f c1 = {b1v[4], b1v[5], b1v[6], b1v[7]};
        c0 = MFMA16(fW1[0], a1h, c0);
        c1 = MFMA16(fW1[1], a1h, c1);
        v4h a2h0, a2h1; float sp2[8];
        #pragma unroll
        for (int i = 0; i < 4; ++i) {
            float a = softplus_f(c0[i]);
            sp2[i] = 1.0f - __expf(-a);
            a2h0[i] = (_Float16)a;
            float b = softplus_f(c1[i]);
            sp2[4 + i] = 1.0f - __expf(-b);
            a2h1[i] = (_Float16)b;
        }
        // ---- L3: 32 = W2(32x32)*a2 + b2 ----
        v4f d0 = {b2v[0], b2v[1], b2v[2], b2v[3]};
        v4f d1 = {b2v[4], b2v[5], b2v[6], b2v[7]};
        d0 = MFMA16(fW2[0][0], a2h0, d0);
        d0 = MFMA16(fW2[0][1], a2h1, d0);
        d1 = MFMA16(fW2[1][0], a2h0, d1);
        d1 = MFMA16(fW2[1][1], a2h1, d1);
        v4h a3h0, a3h1; float sp3[8];
        #pragma unroll
        for (int i = 0; i < 4; ++i) {
            float a = softplus_f(d0[i]);
            sp3[i] = 1.0f - __expf(-a);
            a3h0[i] = (_Float16)a;
            float b = softplus_f(d1[i]);
            sp3[4 + i] = 1.0f - __expf(-b);
            a3h1[i] = (_Float16)b;
        }
        // ---- L4: 16 = W3(16x32)*a3 + b3 ----
        v4f e = {b3v[0], b3v[1], b3v[2], b3v[3]};
        e = MFMA16(fW3[0], a3h0, e);
        e = MFMA16(fW3[1], a3h1, e);
        // ---- g4 = w4 .* sigma'(z4);  sigma' = 1 - exp(-softplus(z)) ----
        v4h g4h;
        #pragma unroll
        for (int i = 0; i < 4; ++i) {
            float a = softplus_f(e[i]);
            g4h[i] = (_Float16)(w4v[i] * (1.0f - __expf(-a)));
        }
        // ---- g3 = (W3^T * g4) .* sp3 ----
        v4f s0 = MFMA16(fW3T[0], g4h, zf);
        v4f s1 = MFMA16(fW3T[1], g4h, zf);
        v4h g3h0, g3h1;
        #pragma unroll
        for (int i = 0; i < 4; ++i) {
            g3h0[i] = (_Float16)(s0[i] * sp3[i]);
            g3h1[i] = (_Float16)(s1[i] * sp3[4 + i]);
        }
        // ---- g2 = (W2^T * g3) .* sp2 ----
        v4f u0 = MFMA16(fW2T[0][0], g3h0, zf);
        u0 = MFMA16(fW2T[0][1], g3h1, u0);
        v4f u1 = MFMA16(fW2T[1][0], g3h0, zf);
        u1 = MFMA16(fW2T[1][1], g3h1, u1);
        v4h g2h0, g2h1;
        #pragma unroll
        for (int i = 0; i < 4; ++i) {
            g2h0[i] = (_Float16)(u0[i] * sp2[i]);
            g2h1[i] = (_Float16)(u1[i] * sp2[4 + i]);
        }
        // ---- g1 = (W1^T * g2) .* sp1 ----
        v4f v0 = MFMA16(fW1T[0], g2h0, zf);
        v0 = MFMA16(fW1T[1], g2h1, v0);
        v4h g1h;
        #pragma unroll
        for (int i = 0; i < 4; ++i)
            g1h[i] = (_Float16)(v0[i] * sp1[i]);
        // ---- gy = W0^T * g1  (rows 0,1 land in g==0 lanes, regs 0,1) ----
        v4f gy = MFMA16(fW0T, g1h, zf);

        y0 = fmaf(-(gy[0] + tilt0), DT_F, y0);
        y1 = fmaf(-(gy[1] + tilt1), DT_F, y1);
        ts += DT_F;

        fY[0] = (g == 0) ? (_Float16)y0 : (_Float16)0.f;
        fY[1] = (g == 0) ? (_Float16)y1 : (_Float16)0.f;
    }

    if (g == 0) {
        out[2 * p + 0] = y0;
        out[2 * p + 1] = y1;
    }
}

extern "C" void kernel_launch(void* const* d_in, const int* in_sizes, int n_in,
                              void* d_out, int out_size, void* d_ws, size_t ws_size,
                              hipStream_t stream) {
    (void)in_sizes; (void)n_in; (void)d_ws; (void)ws_size; (void)out_size;
    const float* w0 = (const float*)d_in[0];
    const float* b0 = (const float*)d_in[1];
    const float* w1 = (const float*)d_in[2];
    const float* b1 = (const float*)d_in[3];
    const float* w2 = (const float*)d_in[4];
    const float* b2 = (const float*)d_in[5];
    const float* w3 = (const float*)d_in[6];
    const float* b3 = (const float*)d_in[7];
    const float* w4 = (const float*)d_in[8];
    const float* b4 = (const float*)d_in[9];
    const float* wt = (const float*)d_in[10];
    const float* x  = (const float*)d_in[11];
    float* out = (float*)d_out;

    dim3 grid(NWAVES), block(64);
    hipLaunchKernelGGL(phinn_kernel, grid, block, 0, stream,
                       w0, b0, w1, b1, w2, b2, w3, b3, w4, b4, wt, x, out);
}